// Round 7
// baseline (1729.095 us; speedup 1.0000x reference)
//
#include <hip/hip_runtime.h>
#include <hip/hip_bf16.h>
#include <math.h>

#define B_ 16
#define C_ 32
#define N_ 500
#define T_ 64
#define L_ 4
#define BSTR (C_*N_*T_)              // 1024000
#define CSTR (N_*T_)                 // 32000
#define TENS ((size_t)B_*C_*N_*T_)   // 16384000
#define CNT_ 512000.0

typedef short s8v __attribute__((ext_vector_type(8)));
typedef float f4v __attribute__((ext_vector_type(4)));
typedef unsigned short u16;

// ---------------------------------------------------------------------------
__global__ __launch_bounds__(256) void zero_kernel(double* __restrict__ p,
                                                   float* __restrict__ slack) {
  p[threadIdx.x] = 0.0;   // 256 doubles = L_*64 stats slots
  if (threadIdx.x < 16) slack[threadIdx.x] = 0.f;  // Yt tail guard (NaN-safe)
}

// ---------------------------------------------------------------------------
// Per-channel sum/sum-sq for BN, layer 0 only (reads x). fp64 exact.
__global__ __launch_bounds__(256) void stats_kernel(const float* __restrict__ h,
                                                    double* __restrict__ st) {
  int c = blockIdx.x, b = blockIdx.y, tid = threadIdx.x;
  const float4* p = (const float4*)(h + (size_t)b*BSTR + (size_t)c*CSTR);
  double s = 0.0, s2 = 0.0;
  for (int i = tid; i < CSTR/4; i += 256) {
    float4 v = p[i];
    s  += (double)v.x + (double)v.y + (double)v.z + (double)v.w;
    s2 += (double)v.x*v.x + (double)v.y*v.y + (double)v.z*v.z + (double)v.w*v.w;
  }
  __shared__ double sd[256], sd2[256];
  sd[tid] = s; sd2[tid] = s2; __syncthreads();
  for (int off = 128; off > 0; off >>= 1) {
    if (tid < off) { sd[tid] += sd[tid+off]; sd2[tid] += sd2[tid+off]; }
    __syncthreads();
  }
  if (tid == 0) { atomicAdd(&st[2*c], sd[0]); atomicAdd(&st[2*c+1], sd2[0]); }
}

// ---------------------------------------------------------------------------
// Build ATcat[w][k] bf16 single plane, w<512 (pad), k-map: [0,500) sup1 v=k,
// [500,1000) sup2 v=k-500, [1000,1024) ZERO (guards B's row-spill reads).
__global__ __launch_bounds__(256) void aconv_kernel(const float* __restrict__ sup,
                                                    short* __restrict__ ATh) {
  int idx = blockIdx.x*256 + threadIdx.x;   // 512*1024
  int k = idx & 1023, w = idx >> 10;
  float val = 0.f;
  if (k < 1000 && w < N_) {
    int s = k >= 500;
    int v = k - s*500;
    val = sup[((size_t)s*N_ + v)*N_ + w];
  }
  __hip_bfloat16 bh = __float2bfloat16(val);
  ATh[idx] = *(short*)&bh;
}

// ---------------------------------------------------------------------------
// One-time W1 transpose: W1T[c][k] = W1[k][c], 2048 elems.
__global__ __launch_bounds__(256) void w1t_kernel(const float* __restrict__ W1,
                                                  float* __restrict__ W1T) {
  int idx = blockIdx.x*256 + threadIdx.x;   // 2048
  int c = idx >> 6, k = idx & 63;
  W1T[c*64 + k] = W1[k*32 + c];
}

// ---------------------------------------------------------------------------
// Weight prep for MFMA fuse4: B-fragment layouts [col][k=c] bf16 hi/lo.
// WAG[l][tap][col(64: 0-31 aff, 32-63 gate)][c(32)], WR[l][o(32)][c(32)].
__global__ __launch_bounds__(256) void wprep_kernel(
    const float* __restrict__ aw, const float* __restrict__ gw,
    const float* __restrict__ rw,
    u16* __restrict__ wagh, u16* __restrict__ wagl,
    u16* __restrict__ wrh,  u16* __restrict__ wrl)
{
  int idx = blockIdx.x*256 + threadIdx.x;   // 0..28671
  if (idx >= 28672) return;
  float v; u16 *dh, *dl; int di;
  if (idx < 24576) {
    int l = idx / 6144, r = idx % 6144;
    int tap = r / 2048, col = (r >> 5) & 63, c = r & 31;
    v = (col < 32) ? aw[l*3072 + (col*32 + c)*3 + tap]
                   : gw[l*3072 + ((col-32)*32 + c)*3 + tap];
    dh = wagh; dl = wagl; di = idx;
  } else {
    int j = idx - 24576;
    int l = j >> 10, o = (j >> 5) & 31, c = j & 31;
    v = rw[l*1024 + o*32 + c];
    dh = wrh; dl = wrl; di = j;
  }
  __hip_bfloat16 bh = __float2bfloat16(v);
  float fh = __bfloat162float(bh);
  __hip_bfloat16 bl = __float2bfloat16(v - fh);
  dh[di] = *(u16*)&bh;
  dl[di] = *(u16*)&bl;
}

// ---------------------------------------------------------------------------
// MFMA fuse: BN -> ReLU -> split-bf16 {res 1x1, causal convs K=3} on matrix
// cores -> tanh*sigmoid in C-fragments -> z to LDS -> VALU 32x96 mix.
// Writes Y0 (float) + Y1h/Y2h (bf16 [o][n][t]).
__global__ __launch_bounds__(512) void fuse4_kernel(
    const float* __restrict__ h, const double* __restrict__ st,
    const float* __restrict__ gamma, const float* __restrict__ beta,
    const u16* __restrict__ wagh, const u16* __restrict__ wagl,
    const u16* __restrict__ wrh,  const u16* __restrict__ wrl,
    const float* __restrict__ rb, const float* __restrict__ ab,
    const float* __restrict__ gb,
    const float* __restrict__ gcw, const float* __restrict__ gcb,
    float* __restrict__ Y0, u16* __restrict__ Y1h, u16* __restrict__ Y2h)
{
  __shared__ __align__(16) char smem[41600];
  __shared__ float ssc[C_], ssb[C_];
  u16* Sxh = (u16*)smem;          // x planes [132 rows][40] (2 pad rows/node)
  u16* Sxl = Sxh + 5280;
  u16* Shh = Sxl + 5280;          // h planes [128][40]
  u16* Shl = Shh + 5120;
  float* Sz = (float*)smem;       // overlay after GEMM: z [2][32*65]

  int tid = threadIdx.x;
  int bx  = blockIdx.x;
  int b = bx / 250, np = bx - b*250;
  size_t off0 = (size_t)b*BSTR + (size_t)(np*2)*T_;

  // ---- stage: 8 f32/thread (coalesced: consecutive tid -> consecutive m)
  int m  = tid & 127;             // m = nn*64 + t  (T_=64)
  int c0 = (tid >> 7) << 3;       // 8-channel group
  float hv[8];
  #pragma unroll
  for (int j = 0; j < 8; j++)
    hv[j] = h[off0 + (size_t)(c0 + j)*CSTR + m];

  if (tid < C_) {
    double mm = st[2*tid] * (1.0/CNT_);
    double vv = st[2*tid+1] * (1.0/CNT_) - mm*mm;
    float sc = gamma[tid] * (float)(1.0 / sqrt(vv + 1e-5));
    ssc[tid] = sc;
    ssb[tid] = beta[tid] - (float)mm * sc;
  }
  __syncthreads();

  union P { u16 s[8]; int4 v; };
  P hh8, hl8, xh8, xl8;
  #pragma unroll
  for (int j = 0; j < 8; j++) {
    float hval = hv[j];
    __hip_bfloat16 t1 = __float2bfloat16(hval);
    hh8.s[j] = *(u16*)&t1;
    __hip_bfloat16 t2 = __float2bfloat16(hval - __bfloat162float(t1));
    hl8.s[j] = *(u16*)&t2;
    float xval = fmaxf(fmaf(hval, ssc[c0+j], ssb[c0+j]), 0.f);
    __hip_bfloat16 t3 = __float2bfloat16(xval);
    xh8.s[j] = *(u16*)&t3;
    __hip_bfloat16 t4 = __float2bfloat16(xval - __bfloat162float(t3));
    xl8.s[j] = *(u16*)&t4;
  }
  *(int4*)&Shh[m*40 + c0] = hh8.v;
  *(int4*)&Shl[m*40 + c0] = hl8.v;
  int xrow = m + 2 + (m >> 6)*2;  // node*66 + tloc + 2
  *(int4*)&Sxh[xrow*40 + c0] = xh8.v;
  *(int4*)&Sxl[xrow*40 + c0] = xl8.v;
  if (tid < 32) {                 // zero pad rows {0,1,66,67} x 2 planes
    int pl = tid >> 4, rsel = (tid >> 2) & 3, ch = tid & 3;
    int row = (rsel & 1) + (rsel >> 1)*66;
    int4 z4 = {0,0,0,0};
    *(int4*)((pl ? Sxl : Sxh) + row*40 + ch*8) = z4;
  }
  __syncthreads();

  // ---- GEMM phase: wave -> 16-row m-tile (node, t0), all 32 out channels
  int lane = tid & 63;
  int wave = __builtin_amdgcn_readfirstlane(tid >> 6);
  int node = wave >> 2, t0 = (wave & 3) << 4;
  int l15 = lane & 15, q = lane >> 4;

  f4v affc[2], gatec[2], resc[2];
  #pragma unroll
  for (int i = 0; i < 2; i++) {
    affc[i] = (f4v){0.f,0.f,0.f,0.f};
    gatec[i] = (f4v){0.f,0.f,0.f,0.f};
    resc[i] = (f4v){0.f,0.f,0.f,0.f};
  }

  {   // res: A = h planes, K=32
    int ha = (node*64 + t0 + l15)*40 + q*8;
    s8v hhf = *(const s8v*)&Shh[ha];
    s8v hlf = *(const s8v*)&Shl[ha];
    #pragma unroll
    for (int ct = 0; ct < 2; ct++) {
      int wb = (ct*16 + l15)*32 + q*8;
      s8v wh = *(const s8v*)&wrh[wb];
      s8v wl = *(const s8v*)&wrl[wb];
      f4v d = resc[ct];
      d = __builtin_amdgcn_mfma_f32_16x16x32_bf16(hhf, wh, d, 0, 0, 0);
      d = __builtin_amdgcn_mfma_f32_16x16x32_bf16(hlf, wh, d, 0, 0, 0);
      d = __builtin_amdgcn_mfma_f32_16x16x32_bf16(hhf, wl, d, 0, 0, 0);
      resc[ct] = d;
    }
  }
  #pragma unroll
  for (int tap = 0; tap < 3; tap++) {   // causal conv = 3 shifted-row GEMMs
    int xa = (node*66 + t0 + l15 + tap)*40 + q*8;
    s8v xhf = *(const s8v*)&Sxh[xa];
    s8v xlf = *(const s8v*)&Sxl[xa];
    #pragma unroll
    for (int ct = 0; ct < 4; ct++) {    // 0,1 aff cols; 2,3 gate cols
      int wb = (tap*64 + ct*16 + l15)*32 + q*8;
      s8v wh = *(const s8v*)&wagh[wb];
      s8v wl = *(const s8v*)&wagl[wb];
      f4v d = (ct < 2) ? affc[ct] : gatec[ct-2];
      d = __builtin_amdgcn_mfma_f32_16x16x32_bf16(xhf, wh, d, 0, 0, 0);
      d = __builtin_amdgcn_mfma_f32_16x16x32_bf16(xlf, wh, d, 0, 0, 0);
      d = __builtin_amdgcn_mfma_f32_16x16x32_bf16(xhf, wl, d, 0, 0, 0);
      if (ct < 2) affc[ct] = d; else gatec[ct-2] = d;
    }
  }
  __syncthreads();   // all LDS A-reads done before z overlays the planes

  // ---- combine in C-fragment layout: col=o=l15(+16ct), row m=t0+q*4+r
  #pragma unroll
  for (int ct = 0; ct < 2; ct++) {
    int o = ct*16 + l15;
    float abias = ab[o] + rb[o];
    float gbias = gb[o];
    #pragma unroll
    for (int r = 0; r < 4; r++) {
      float a = affc[ct][r] + resc[ct][r] + abias;
      float g = gatec[ct][r] + gbias;
      float z = tanhf(a) * (1.f/(1.f + expf(-g)));
      Sz[node*2080 + o*65 + (t0 + q*4 + r)] = z;
    }
  }
  __syncthreads();

  // ---- mix: three 32x32 pointwise GEMMs on VALU (proven epilogue)
  int t = tid & 63;
  int og = wave;
  float y0a[2][4] = {}, y1a[2][4] = {}, y2a[2][4] = {};
  for (int c = 0; c < C_; c++) {
    float g0[4], g1[4], g2[4];
    #pragma unroll
    for (int jq = 0; jq < 4; jq++) {
      const float* gr = gcw + (og*4 + jq)*96;
      g0[jq] = gr[c]; g1[jq] = gr[32 + c]; g2[jq] = gr[64 + c];
    }
    #pragma unroll
    for (int nn = 0; nn < 2; nn++) {
      float zc = Sz[nn*2080 + c*65 + t];
      #pragma unroll
      for (int jq = 0; jq < 4; jq++) {
        y0a[nn][jq] = fmaf(g0[jq], zc, y0a[nn][jq]);
        y1a[nn][jq] = fmaf(g1[jq], zc, y1a[nn][jq]);
        y2a[nn][jq] = fmaf(g2[jq], zc, y2a[nn][jq]);
      }
    }
  }
  #pragma unroll
  for (int nn = 0; nn < 2; nn++)
    #pragma unroll
    for (int jq = 0; jq < 4; jq++) {
      int oo = og*4 + jq;
      size_t pp = off0 + (size_t)nn*T_ + (size_t)oo*CSTR + t;
      Y0[pp] = y0a[nn][jq] + gcb[oo];
      __hip_bfloat16 b1 = __float2bfloat16(y1a[nn][jq]);
      __hip_bfloat16 b2 = __float2bfloat16(y2a[nn][jq]);
      Y1h[pp] = *(u16*)&b1;
      Y2h[pp] = *(u16*)&b2;
    }
}

// ---------------------------------------------------------------------------
// Transpose Y1h/Y2h [o][n][t] -> Yt [b][(o*64+t)][1000 v-contig] (v<500 sup1,
// 500..999 sup2), zero-padding internally. LDS 64x68 tile; paired b32 reads.
__global__ __launch_bounds__(256) void trans_kernel(
    const u16* __restrict__ Y1h, const u16* __restrict__ Y2h,
    u16* __restrict__ Yt)
{
  __shared__ u16 S[64*68];
  int bx = blockIdx.x;
  int o = bx & 31, vg = bx >> 5;       // 32 o x 4 vgroups
  int b = blockIdx.y;
  int tid = threadIdx.x;
  u16* dst = Yt + (size_t)(b*C_ + o)*64000;
  for (int ic = 0; ic < 4; ic++) {
    int vc = vg*4 + ic;                // 64-v chunk, 0..15
    __syncthreads();
    #pragma unroll
    for (int i = 0; i < 2; i++) {
      int vrow = (tid >> 3) + i*32;
      int vv = vc*64 + vrow;           // concat-v 0..1023
      int t8 = (tid & 7)*8;
      int4 val = {0,0,0,0};
      if (vv < 1000) {
        int sup = vv >= 500;
        int n = vv - sup*500;
        const u16* src = (sup ? Y2h : Y1h) + (size_t)b*BSTR + (size_t)o*CSTR
                         + (size_t)n*T_;
        val = *(const int4*)(src + t8);
      }
      *(int4*)&S[vrow*68 + t8] = val;
    }
    __syncthreads();
    int t2 = tid >> 3, vs = tid & 7;   // t = 2*t2, 2*t2+1; v-oct vs
    if (vc < 15 || vs < 5) {           // rows >= 1000 don't exist in dst
      unsigned r[8];
      #pragma unroll
      for (int j = 0; j < 8; j++)
        r[j] = *(const unsigned*)&S[(vs*8 + j)*68 + 2*t2];
      u16 lo[8], hi[8];
      #pragma unroll
      for (int j = 0; j < 8; j++) { lo[j] = (u16)r[j]; hi[j] = (u16)(r[j] >> 16); }
      *(int4*)(dst + (size_t)(2*t2)*1000   + vc*64 + vs*8) = *(const int4*)lo;
      *(int4*)(dst + (size_t)(2*t2+1)*1000 + vc*64 + vs*8) = *(const int4*)hi;
    }
  }
}

// ---------------------------------------------------------------------------
// Diffusion GEMM, zero LDS / zero barriers. Round-6 diagnosis: HBM-miss
// latency (MfmaUtil 9%) from XCD L2 thrash (6 b-slices live) + shallow
// pipeline. Fixes: (1) bijective XCD swizzle so each XCD works ONE b-slice
// (4MB = its L2; Yt fetched from HBM once, 8x wtile reuse becomes L2-hit);
// (2) depth-2 register pipeline (3 named buffer sets, static rotation) so
// load->consume distance covers L2 latency. Fused BN stats epilogue.
__global__ __launch_bounds__(256) void diff4_kernel(
    const u16* __restrict__ Yt,
    const short* __restrict__ ATh,
    float* __restrict__ out, double* __restrict__ stp)
{
  int tid = threadIdx.x;
  int lin = blockIdx.x;                   // 2048 blocks, 1-D
  int xcd = lin & 7;
  int b = xcd*2 + (lin >> 10);            // each XCD: one b at a time
  int x = (lin >> 3) & 127;
  int mtile = x & 15, wtile = x >> 4;     // 16 mtiles x 8 wtiles
  int w0 = wtile << 6;

  int lane = tid & 63;
  int wave = __builtin_amdgcn_readfirstlane(tid >> 6);
  int wi = wave & 1, wj = wave >> 1;
  int l15 = lane & 15, quad = lane >> 4;
  int o = mtile*2 + wj;

  const short* pA[2]; const u16* pB[4];
  #pragma unroll
  for (int ti = 0; ti < 2; ti++)
    pA[ti] = ATh + (size_t)(w0 + wi*32 + ti*16 + l15)*1024 + quad*8;
  const u16* Ybase = Yt + (size_t)(b*C_ + o)*64000;
  #pragma unroll
  for (int tj = 0; tj < 4; tj++)
    pB[tj] = Ybase + (size_t)(tj*16 + l15)*1000 + quad*8;

  f4v acc[8];
  #pragma unroll
  for (int i = 0; i < 8; i++) acc[i] = (f4v){0.f, 0.f, 0.f, 0.f};

  s8v aA[2], bA[4], aB[2], bB[4], aC[2], bC[4];

  auto LOADS = [&](s8v (&av)[2], s8v (&bv)[4], int k0) {
    #pragma unroll
    for (int ti = 0; ti < 2; ti++) av[ti] = *(const s8v*)(pA[ti] + k0);
    #pragma unroll
    for (int tj = 0; tj < 4; tj++) bv[tj] = *(const s8v*)(pB[tj] + k0);
  };
  auto MM = [&](s8v (&av)[2], s8v (&bv)[4]) {
    #pragma unroll
    for (int ti = 0; ti < 2; ti++)
      #pragma unroll
      for (int tj = 0; tj < 4; tj++)
        acc[ti*4+tj] = __builtin_amdgcn_mfma_f32_16x16x32_bf16(
                           av[ti], bv[tj], acc[ti*4+tj], 0, 0, 0);
  };

  // 32 k-steps of 32; depth-2: loads run 2 steps ahead of consumption.
  LOADS(aA, bA, 0);
  LOADS(aB, bB, 32);
  int k = 64;
  for (int it = 0; it < 10; ++it) {       // 30 steps (static buffer rotation)
    LOADS(aC, bC, k); MM(aA, bA); k += 32;
    LOADS(aA, bA, k); MM(aB, bB); k += 32;
    LOADS(aB, bB, k); MM(aC, bC); k += 32;
  }
  MM(aA, bA);                             // k-steps 30, 31
  MM(aB, bB);

  // epilogue: out += acc; capture final values for next layer's BN stats.
  float s = 0.f, s2 = 0.f;
  #pragma unroll
  for (int tj = 0; tj < 4; tj++) {
    int t = tj*16 + l15;
    float* obase = out + (((size_t)b*C_ + o)*N_)*T_ + t;
    #pragma unroll
    for (int ti = 0; ti < 2; ti++) {
      int wbase = w0 + wi*32 + ti*16 + quad*4;
      #pragma unroll
      for (int r = 0; r < 4; r++) {
        int w = wbase + r;
        if (w < N_) {
          float* p = obase + (size_t)w*T_;
          float val = *p + acc[ti*4+tj][r];
          *p = val;
          s += val;
          s2 = fmaf(val, val, s2);
        }
      }
    }
  }
  if (stp) {
    #pragma unroll
    for (int d = 32; d > 0; d >>= 1) {
      s  += __shfl_down(s,  d, 64);
      s2 += __shfl_down(s2, d, 64);
    }
    if (lane == 0) {
      atomicAdd(&stp[2*o],     (double)s);
      atomicAdd(&stp[2*o + 1], (double)s2);
    }
  }
}

// ---------------------------------------------------------------------------
// Online-softmax attention, one node per wave, MLP fully in registers.
__global__ __launch_bounds__(256) void attn3_kernel(
    const float* __restrict__ hsrc, float* __restrict__ O,
    float* __restrict__ sden,
    const float* __restrict__ W1T, const float* __restrict__ b1,
    const float* __restrict__ W2, const float* __restrict__ b2,
    const float* __restrict__ w3, const float* __restrict__ b3,
    int init)
{
  int tid = threadIdx.x;
  int t = tid & 63;
  int g = __builtin_amdgcn_readfirstlane(tid >> 6);
  int bx = blockIdx.x;
  int b = bx / 125;
  int n = (bx - b*125)*4 + g;
  size_t off = (size_t)b*BSTR + (size_t)n*T_;

  float h1r[64];
  #pragma unroll
  for (int k = 0; k < 64; k++) h1r[k] = b1[k];
  for (int c = 0; c < C_; c++) {
    float xv = fmaxf(hsrc[off + (size_t)c*CSTR + t], 0.f);
    const float* wr = W1T + c*64;
    #pragma unroll
    for (int k = 0; k < 64; k++) h1r[k] = fmaf(wr[k], xv, h1r[k]);
  }
  #pragma unroll
  for (int k = 0; k < 64; k++) h1r[k] = fmaxf(h1r[k], 0.f);

  float e = b3[0];
  for (int j = 0; j < 64; j++) {
    const float* w2r = W2 + j*64;
    float a0 = 0.f, a1 = 0.f, a2 = 0.f, a3 = 0.f;
    #pragma unroll
    for (int i = 0; i < 64; i += 4) {
      a0 = fmaf(w2r[i+0], h1r[i+0], a0);
      a1 = fmaf(w2r[i+1], h1r[i+1], a1);
      a2 = fmaf(w2r[i+2], h1r[i+2], a2);
      a3 = fmaf(w2r[i+3], h1r[i+3], a3);
    }
    float a = b2[j] + ((a0+a1)+(a2+a3));
    e = fmaf(w3[j], fmaxf(a, 0.f), e);
  }
  float p = expf(e);      // e is O(1): no max-subtraction needed

  size_t si = (size_t)b*CSTR + (size_t)n*T_ + t;
  float so = init ? 0.f : sden[si];
  sden[si] = so + p;

  for (int c = 0; c < C_; c++) {
    size_t pi = off + (size_t)c*CSTR + t;
    float xv = fmaxf(hsrc[pi], 0.f);      // L1-hit re-read
    float ov = init ? 0.f : O[pi];
    O[pi] = fmaf(p, xv, ov);
  }
}

// ---------------------------------------------------------------------------
__global__ __launch_bounds__(256) void norm_kernel(float* __restrict__ O,
                                                   const float* __restrict__ sden) {
  unsigned idx = (blockIdx.x*256u + threadIdx.x) * 4u;
  unsigned b = idx / BSTR;
  unsigned r = idx - b*BSTR;
  unsigned nt = r % CSTR;
  float4 o = *(float4*)(O + idx);
  const float* sp = sden + (size_t)b*CSTR + nt;
  o.x /= sp[0]; o.y /= sp[1]; o.z /= sp[2]; o.w /= sp[3];
  *(float4*)(O + idx) = o;
}

// ---------------------------------------------------------------------------
extern "C" void kernel_launch(void* const* d_in, const int* in_sizes, int n_in,
                              void* d_out, int out_size, void* d_ws, size_t ws_size,
                              hipStream_t stream)
{
  const float* x    = (const float*)d_in[0];
  const float* sup  = (const float*)d_in[1];
  const float* bng  = (const float*)d_in[2];
  const float* bnb  = (const float*)d_in[3];
  const float* rw   = (const float*)d_in[4];
  const float* rb   = (const float*)d_in[5];
  const float* aw   = (const float*)d_in[6];
  const float* ab   = (const float*)d_in[7];
  const float* gw   = (const float*)d_in[8];
  const float* gb   = (const float*)d_in[9];
  const float* gcw  = (const float*)d_in[10];
  const float* gcb  = (const float*)d_in[11];
  const float* w1   = (const float*)d_in[12];
  const float* ab1  = (const float*)d_in[13];
  const float* w2   = (const float*)d_in[14];
  const float* ab2  = (const float*)d_in[15];
  const float* w3   = (const float*)d_in[16];
  const float* ab3  = (const float*)d_in[17];
  float* out = (float*)d_out;

  // ws layout (floats; total 49,957,904 fl = 190.6 MiB < prior 191.6 MiB):
  float* ws   = (float*)d_ws;
  float* bufA = ws;                                   // TENS
  u16*   Y1h  = (u16*)(ws + TENS);                    // TENS u16
  u16*   Y2h  = Y1h + TENS;                           // TENS u16
  u16*   Yt   = (u16*)(ws + (size_t)2*TENS);          // 16*2048*1000 u16
  float* slack= ws + (size_t)2*TENS + 16384000;       // 16 fl (Yt spill guard)
  float* sden = slack + 16;                           // 512000
  double* st  = (double*)(sden + (size_t)B_*N_*T_);   // 512 dbl
  short* ATh  = (short*)((float*)st + 1024);          // 512*1024 shorts
  float* W1T  = (float*)(ATh + (size_t)512*1024);     // 2048
  u16* WAGh = (u16*)(W1T + 2048);                     // [L][3][64][32]
  u16* WAGl = WAGh + 24576;
  u16* WRh  = WAGl + 24576;                           // [L][32][32]
  u16* WRl  = WRh + 4096;

  zero_kernel<<<1, 256, 0, stream>>>(st, slack);
  aconv_kernel<<<2048, 256, 0, stream>>>(sup, ATh);
  w1t_kernel<<<8, 256, 0, stream>>>(w1, W1T);
  wprep_kernel<<<112, 256, 0, stream>>>(aw, gw, rw, WAGh, WAGl, WRh, WRl);
  stats_kernel<<<dim3(C_, B_), 256, 0, stream>>>(x, st);
  // slot 0 of the stack = x
  attn3_kernel<<<B_*125, 256, 0, stream>>>(x, out, sden, W1T, ab1, w2, ab2, w3, ab3, 1);

  const float* hcur = x;
  for (int l = 0; l < L_; l++) {
    fuse4_kernel<<<B_*250, 512, 0, stream>>>(
        hcur, st + l*64, bng + l*C_, bnb + l*C_,
        WAGh + l*6144, WAGl + l*6144, WRh + l*1024, WRl + l*1024,
        rb + l*C_, ab + l*C_, gb + l*C_,
        gcw + l*C_*96, gcb + l*C_,
        bufA, Y1h, Y2h);
    trans_kernel<<<dim3(128, B_), 256, 0, stream>>>(Y1h, Y2h, Yt);
    diff4_kernel<<<2048, 256, 0, stream>>>(
        Yt, ATh, bufA, (l < L_-1) ? (st + (l+1)*64) : nullptr);
    attn3_kernel<<<B_*125, 256, 0, stream>>>(bufA, out, sden, W1T, ab1, w2, ab2, w3, ab3, 0);
    hcur = bufA;
  }
  norm_kernel<<<16000, 256, 0, stream>>>(out, sden);
}

// Round 8
// 1637.521 us; speedup vs baseline: 1.0559x; 1.0559x over previous
//
#include <hip/hip_runtime.h>
#include <hip/hip_bf16.h>
#include <math.h>

#define B_ 16
#define C_ 32
#define N_ 500
#define T_ 64
#define L_ 4
#define BSTR (C_*N_*T_)              // 1024000
#define CSTR (N_*T_)                 // 32000
#define TENS ((size_t)B_*C_*N_*T_)   // 16384000
#define CNT_ 512000.0

typedef short s8v __attribute__((ext_vector_type(8)));
typedef float f4v __attribute__((ext_vector_type(4)));
typedef unsigned short u16;

// ---------------------------------------------------------------------------
__global__ __launch_bounds__(256) void zero_kernel(double* __restrict__ p,
                                                   float* __restrict__ slack) {
  p[threadIdx.x] = 0.0;   // 256 doubles = L_*64 stats slots
  if (threadIdx.x < 16) slack[threadIdx.x] = 0.f;  // Yt tail guard (NaN-safe)
}

// ---------------------------------------------------------------------------
// Per-channel sum/sum-sq for BN, layer 0 only (reads x). fp64 exact.
__global__ __launch_bounds__(256) void stats_kernel(const float* __restrict__ h,
                                                    double* __restrict__ st) {
  int c = blockIdx.x, b = blockIdx.y, tid = threadIdx.x;
  const float4* p = (const float4*)(h + (size_t)b*BSTR + (size_t)c*CSTR);
  double s = 0.0, s2 = 0.0;
  for (int i = tid; i < CSTR/4; i += 256) {
    float4 v = p[i];
    s  += (double)v.x + (double)v.y + (double)v.z + (double)v.w;
    s2 += (double)v.x*v.x + (double)v.y*v.y + (double)v.z*v.z + (double)v.w*v.w;
  }
  __shared__ double sd[256], sd2[256];
  sd[tid] = s; sd2[tid] = s2; __syncthreads();
  for (int off = 128; off > 0; off >>= 1) {
    if (tid < off) { sd[tid] += sd[tid+off]; sd2[tid] += sd2[tid+off]; }
    __syncthreads();
  }
  if (tid == 0) { atomicAdd(&st[2*c], sd[0]); atomicAdd(&st[2*c+1], sd2[0]); }
}

// ---------------------------------------------------------------------------
// Build ATcat[w][k] bf16 single plane, w<512 (pad), k-map: [0,500) sup1 v=k,
// [500,1000) sup2 v=k-500, [1000,1024) ZERO (guards B's row-spill reads).
__global__ __launch_bounds__(256) void aconv_kernel(const float* __restrict__ sup,
                                                    short* __restrict__ ATh) {
  int idx = blockIdx.x*256 + threadIdx.x;   // 512*1024
  int k = idx & 1023, w = idx >> 10;
  float val = 0.f;
  if (k < 1000 && w < N_) {
    int s = k >= 500;
    int v = k - s*500;
    val = sup[((size_t)s*N_ + v)*N_ + w];
  }
  __hip_bfloat16 bh = __float2bfloat16(val);
  ATh[idx] = *(short*)&bh;
}

// ---------------------------------------------------------------------------
// One-time W1 transpose: W1T[c][k] = W1[k][c], 2048 elems.
__global__ __launch_bounds__(256) void w1t_kernel(const float* __restrict__ W1,
                                                  float* __restrict__ W1T) {
  int idx = blockIdx.x*256 + threadIdx.x;   // 2048
  int c = idx >> 6, k = idx & 63;
  W1T[c*64 + k] = W1[k*32 + c];
}

// ---------------------------------------------------------------------------
// Weight prep for MFMA fuse4: B-fragment layouts [col][k=c] bf16 hi/lo.
// WAG[l][tap][col(64: 0-31 aff, 32-63 gate)][c(32)], WR[l][o(32)][c(32)].
__global__ __launch_bounds__(256) void wprep_kernel(
    const float* __restrict__ aw, const float* __restrict__ gw,
    const float* __restrict__ rw,
    u16* __restrict__ wagh, u16* __restrict__ wagl,
    u16* __restrict__ wrh,  u16* __restrict__ wrl)
{
  int idx = blockIdx.x*256 + threadIdx.x;   // 0..28671
  if (idx >= 28672) return;
  float v; u16 *dh, *dl; int di;
  if (idx < 24576) {
    int l = idx / 6144, r = idx % 6144;
    int tap = r / 2048, col = (r >> 5) & 63, c = r & 31;
    v = (col < 32) ? aw[l*3072 + (col*32 + c)*3 + tap]
                   : gw[l*3072 + ((col-32)*32 + c)*3 + tap];
    dh = wagh; dl = wagl; di = idx;
  } else {
    int j = idx - 24576;
    int l = j >> 10, o = (j >> 5) & 31, c = j & 31;
    v = rw[l*1024 + o*32 + c];
    dh = wrh; dl = wrl; di = j;
  }
  __hip_bfloat16 bh = __float2bfloat16(v);
  float fh = __bfloat162float(bh);
  __hip_bfloat16 bl = __float2bfloat16(v - fh);
  dh[di] = *(u16*)&bh;
  dl[di] = *(u16*)&bl;
}

// ---------------------------------------------------------------------------
// MFMA fuse: BN -> ReLU -> split-bf16 {res 1x1, causal convs K=3} on matrix
// cores -> tanh*sigmoid in C-fragments -> z to LDS -> VALU 32x96 mix.
// Writes Y0 (float) + Y1h/Y2h (bf16 [o][n][t]).
__global__ __launch_bounds__(512) void fuse4_kernel(
    const float* __restrict__ h, const double* __restrict__ st,
    const float* __restrict__ gamma, const float* __restrict__ beta,
    const u16* __restrict__ wagh, const u16* __restrict__ wagl,
    const u16* __restrict__ wrh,  const u16* __restrict__ wrl,
    const float* __restrict__ rb, const float* __restrict__ ab,
    const float* __restrict__ gb,
    const float* __restrict__ gcw, const float* __restrict__ gcb,
    float* __restrict__ Y0, u16* __restrict__ Y1h, u16* __restrict__ Y2h)
{
  __shared__ __align__(16) char smem[41600];
  __shared__ float ssc[C_], ssb[C_];
  u16* Sxh = (u16*)smem;          // x planes [132 rows][40] (2 pad rows/node)
  u16* Sxl = Sxh + 5280;
  u16* Shh = Sxl + 5280;          // h planes [128][40]
  u16* Shl = Shh + 5120;
  float* Sz = (float*)smem;       // overlay after GEMM: z [2][32*65]

  int tid = threadIdx.x;
  int bx  = blockIdx.x;
  int b = bx / 250, np = bx - b*250;
  size_t off0 = (size_t)b*BSTR + (size_t)(np*2)*T_;

  // ---- stage: 8 f32/thread (coalesced: consecutive tid -> consecutive m)
  int m  = tid & 127;             // m = nn*64 + t  (T_=64)
  int c0 = (tid >> 7) << 3;       // 8-channel group
  float hv[8];
  #pragma unroll
  for (int j = 0; j < 8; j++)
    hv[j] = h[off0 + (size_t)(c0 + j)*CSTR + m];

  if (tid < C_) {
    double mm = st[2*tid] * (1.0/CNT_);
    double vv = st[2*tid+1] * (1.0/CNT_) - mm*mm;
    float sc = gamma[tid] * (float)(1.0 / sqrt(vv + 1e-5));
    ssc[tid] = sc;
    ssb[tid] = beta[tid] - (float)mm * sc;
  }
  __syncthreads();

  union P { u16 s[8]; int4 v; };
  P hh8, hl8, xh8, xl8;
  #pragma unroll
  for (int j = 0; j < 8; j++) {
    float hval = hv[j];
    __hip_bfloat16 t1 = __float2bfloat16(hval);
    hh8.s[j] = *(u16*)&t1;
    __hip_bfloat16 t2 = __float2bfloat16(hval - __bfloat162float(t1));
    hl8.s[j] = *(u16*)&t2;
    float xval = fmaxf(fmaf(hval, ssc[c0+j], ssb[c0+j]), 0.f);
    __hip_bfloat16 t3 = __float2bfloat16(xval);
    xh8.s[j] = *(u16*)&t3;
    __hip_bfloat16 t4 = __float2bfloat16(xval - __bfloat162float(t3));
    xl8.s[j] = *(u16*)&t4;
  }
  *(int4*)&Shh[m*40 + c0] = hh8.v;
  *(int4*)&Shl[m*40 + c0] = hl8.v;
  int xrow = m + 2 + (m >> 6)*2;  // node*66 + tloc + 2
  *(int4*)&Sxh[xrow*40 + c0] = xh8.v;
  *(int4*)&Sxl[xrow*40 + c0] = xl8.v;
  if (tid < 32) {                 // zero pad rows {0,1,66,67} x 2 planes
    int pl = tid >> 4, rsel = (tid >> 2) & 3, ch = tid & 3;
    int row = (rsel & 1) + (rsel >> 1)*66;
    int4 z4 = {0,0,0,0};
    *(int4*)((pl ? Sxl : Sxh) + row*40 + ch*8) = z4;
  }
  __syncthreads();

  // ---- GEMM phase: wave -> 16-row m-tile (node, t0), all 32 out channels
  int lane = tid & 63;
  int wave = __builtin_amdgcn_readfirstlane(tid >> 6);
  int node = wave >> 2, t0 = (wave & 3) << 4;
  int l15 = lane & 15, q = lane >> 4;

  f4v affc[2], gatec[2], resc[2];
  #pragma unroll
  for (int i = 0; i < 2; i++) {
    affc[i] = (f4v){0.f,0.f,0.f,0.f};
    gatec[i] = (f4v){0.f,0.f,0.f,0.f};
    resc[i] = (f4v){0.f,0.f,0.f,0.f};
  }

  {   // res: A = h planes, K=32
    int ha = (node*64 + t0 + l15)*40 + q*8;
    s8v hhf = *(const s8v*)&Shh[ha];
    s8v hlf = *(const s8v*)&Shl[ha];
    #pragma unroll
    for (int ct = 0; ct < 2; ct++) {
      int wb = (ct*16 + l15)*32 + q*8;
      s8v wh = *(const s8v*)&wrh[wb];
      s8v wl = *(const s8v*)&wrl[wb];
      f4v d = resc[ct];
      d = __builtin_amdgcn_mfma_f32_16x16x32_bf16(hhf, wh, d, 0, 0, 0);
      d = __builtin_amdgcn_mfma_f32_16x16x32_bf16(hlf, wh, d, 0, 0, 0);
      d = __builtin_amdgcn_mfma_f32_16x16x32_bf16(hhf, wl, d, 0, 0, 0);
      resc[ct] = d;
    }
  }
  #pragma unroll
  for (int tap = 0; tap < 3; tap++) {   // causal conv = 3 shifted-row GEMMs
    int xa = (node*66 + t0 + l15 + tap)*40 + q*8;
    s8v xhf = *(const s8v*)&Sxh[xa];
    s8v xlf = *(const s8v*)&Sxl[xa];
    #pragma unroll
    for (int ct = 0; ct < 4; ct++) {    // 0,1 aff cols; 2,3 gate cols
      int wb = (tap*64 + ct*16 + l15)*32 + q*8;
      s8v wh = *(const s8v*)&wagh[wb];
      s8v wl = *(const s8v*)&wagl[wb];
      f4v d = (ct < 2) ? affc[ct] : gatec[ct-2];
      d = __builtin_amdgcn_mfma_f32_16x16x32_bf16(xhf, wh, d, 0, 0, 0);
      d = __builtin_amdgcn_mfma_f32_16x16x32_bf16(xlf, wh, d, 0, 0, 0);
      d = __builtin_amdgcn_mfma_f32_16x16x32_bf16(xhf, wl, d, 0, 0, 0);
      if (ct < 2) affc[ct] = d; else gatec[ct-2] = d;
    }
  }
  __syncthreads();   // all LDS A-reads done before z overlays the planes

  // ---- combine in C-fragment layout: col=o=l15(+16ct), row m=t0+q*4+r
  #pragma unroll
  for (int ct = 0; ct < 2; ct++) {
    int o = ct*16 + l15;
    float abias = ab[o] + rb[o];
    float gbias = gb[o];
    #pragma unroll
    for (int r = 0; r < 4; r++) {
      float a = affc[ct][r] + resc[ct][r] + abias;
      float g = gatec[ct][r] + gbias;
      float z = tanhf(a) * (1.f/(1.f + expf(-g)));
      Sz[node*2080 + o*65 + (t0 + q*4 + r)] = z;
    }
  }
  __syncthreads();

  // ---- mix: three 32x32 pointwise GEMMs on VALU (proven epilogue)
  int t = tid & 63;
  int og = wave;
  float y0a[2][4] = {}, y1a[2][4] = {}, y2a[2][4] = {};
  for (int c = 0; c < C_; c++) {
    float g0[4], g1[4], g2[4];
    #pragma unroll
    for (int jq = 0; jq < 4; jq++) {
      const float* gr = gcw + (og*4 + jq)*96;
      g0[jq] = gr[c]; g1[jq] = gr[32 + c]; g2[jq] = gr[64 + c];
    }
    #pragma unroll
    for (int nn = 0; nn < 2; nn++) {
      float zc = Sz[nn*2080 + c*65 + t];
      #pragma unroll
      for (int jq = 0; jq < 4; jq++) {
        y0a[nn][jq] = fmaf(g0[jq], zc, y0a[nn][jq]);
        y1a[nn][jq] = fmaf(g1[jq], zc, y1a[nn][jq]);
        y2a[nn][jq] = fmaf(g2[jq], zc, y2a[nn][jq]);
      }
    }
  }
  #pragma unroll
  for (int nn = 0; nn < 2; nn++)
    #pragma unroll
    for (int jq = 0; jq < 4; jq++) {
      int oo = og*4 + jq;
      size_t pp = off0 + (size_t)nn*T_ + (size_t)oo*CSTR + t;
      Y0[pp] = y0a[nn][jq] + gcb[oo];
      __hip_bfloat16 b1 = __float2bfloat16(y1a[nn][jq]);
      __hip_bfloat16 b2 = __float2bfloat16(y2a[nn][jq]);
      Y1h[pp] = *(u16*)&b1;
      Y2h[pp] = *(u16*)&b2;
    }
}

// ---------------------------------------------------------------------------
// Transpose Y1h/Y2h [o][n][t] -> Yt [b][(o*64+t)][1000 v-contig] (v<500 sup1,
// 500..999 sup2), zero-padding internally. LDS 64x68 tile; paired b32 reads.
__global__ __launch_bounds__(256) void trans_kernel(
    const u16* __restrict__ Y1h, const u16* __restrict__ Y2h,
    u16* __restrict__ Yt)
{
  __shared__ u16 S[64*68];
  int bx = blockIdx.x;
  int o = bx & 31, vg = bx >> 5;       // 32 o x 4 vgroups
  int b = blockIdx.y;
  int tid = threadIdx.x;
  u16* dst = Yt + (size_t)(b*C_ + o)*64000;
  for (int ic = 0; ic < 4; ic++) {
    int vc = vg*4 + ic;                // 64-v chunk, 0..15
    __syncthreads();
    #pragma unroll
    for (int i = 0; i < 2; i++) {
      int vrow = (tid >> 3) + i*32;
      int vv = vc*64 + vrow;           // concat-v 0..1023
      int t8 = (tid & 7)*8;
      int4 val = {0,0,0,0};
      if (vv < 1000) {
        int sup = vv >= 500;
        int n = vv - sup*500;
        const u16* src = (sup ? Y2h : Y1h) + (size_t)b*BSTR + (size_t)o*CSTR
                         + (size_t)n*T_;
        val = *(const int4*)(src + t8);
      }
      *(int4*)&S[vrow*68 + t8] = val;
    }
    __syncthreads();
    int t2 = tid >> 3, vs = tid & 7;   // t = 2*t2, 2*t2+1; v-oct vs
    if (vc < 15 || vs < 5) {           // rows >= 1000 don't exist in dst
      unsigned r[8];
      #pragma unroll
      for (int j = 0; j < 8; j++)
        r[j] = *(const unsigned*)&S[(vs*8 + j)*68 + 2*t2];
      u16 lo[8], hi[8];
      #pragma unroll
      for (int j = 0; j < 8; j++) { lo[j] = (u16)r[j]; hi[j] = (u16)(r[j] >> 16); }
      *(int4*)(dst + (size_t)(2*t2)*1000   + vc*64 + vs*8) = *(const int4*)lo;
      *(int4*)(dst + (size_t)(2*t2+1)*1000 + vc*64 + vs*8) = *(const int4*)hi;
    }
  }
}

// ---------------------------------------------------------------------------
// Diffusion GEMM v6: round-4's PROVEN 2-barrier LDS schedule (cross-wave
// overlap hides latency; zero-LDS variants r6/r7 were latency-bound at 9%
// MfmaUtil) + trans'd Yt (coalesced int4 B-staging replaces the 16-scalar
// gather that made r4 VALU-bound) + single-plane A (validated r6).
// Per k-step/thread: 3 coalesced int4 loads -> 3 ds_writes -> 8 MFMA.
// 2-D grid, natural order: B-reuse blocks 16 apart in dispatch -> L3 absorbs
// (r7 lesson: dispatch-order reuse distance >> XCD pinning).
__global__ __launch_bounds__(256) void diff6_kernel(
    const u16* __restrict__ Yt,
    const short* __restrict__ ATh,
    float* __restrict__ out, double* __restrict__ stp)
{
  __shared__ short Asd[64*40];       // AT tile [w_local][k(32)+pad8]
  __shared__ short Bsd[128*40];      // Y  tile [m=(oo,t)][k(32)+pad8]

  int tid = threadIdx.x;
  int bx = blockIdx.x;
  int mtile = bx & 15, wtile = bx >> 4;   // 16 mtiles x 8 wtiles
  int b = blockIdx.y;
  int w0 = wtile << 6;

  int lane = tid & 63;
  int wave = __builtin_amdgcn_readfirstlane(tid >> 6);
  int wi = wave & 1, wj = wave >> 1;
  int l15 = lane & 15, quad = lane >> 4;
  int o = mtile*2 + wj;

  int offA[2], offB[4];
  #pragma unroll
  for (int ti = 0; ti < 2; ti++) offA[ti] = (wi*32 + ti*16 + l15)*40 + quad*8;
  #pragma unroll
  for (int tj = 0; tj < 4; tj++) offB[tj] = (wj*64 + tj*16 + l15)*40 + quad*8;

  // staging maps (coalesced: consecutive tid -> consecutive 16B within row)
  int akq = tid & 3, awl = tid >> 2;                 // A: 256 int4 = 64r x 4
  const short* aSrc = ATh + (size_t)(w0 + awl)*1024 + akq*8;
  short* aDst = &Asd[awl*40 + akq*8];
  const u16* bSrc[2]; short* bDst[2];
  #pragma unroll
  for (int i = 0; i < 2; i++) {                      // B: 512 int4 = 128r x 4
    int idx = tid + i*256;
    int kq = idx & 3, m = idx >> 2;
    int oo = m >> 6, tl = m & 63;
    bSrc[i] = Yt + ((size_t)(b*C_ + mtile*2 + oo)*64 + tl)*1000 + kq*8;
    bDst[i] = &Bsd[m*40 + kq*8];
  }

  f4v acc[8];
  #pragma unroll
  for (int i = 0; i < 8; i++) acc[i] = (f4v){0.f, 0.f, 0.f, 0.f};

  for (int k0 = 0; k0 < 1024; k0 += 32) {
    __syncthreads();
    *(int4*)aDst    = *(const int4*)(aSrc    + k0);
    *(int4*)bDst[0] = *(const int4*)(bSrc[0] + k0);
    *(int4*)bDst[1] = *(const int4*)(bSrc[1] + k0);
    __syncthreads();
    s8v bv[4];
    #pragma unroll
    for (int tj = 0; tj < 4; tj++) bv[tj] = *(const s8v*)&Bsd[offB[tj]];
    #pragma unroll
    for (int ti = 0; ti < 2; ti++) {
      s8v av = *(const s8v*)&Asd[offA[ti]];
      #pragma unroll
      for (int tj = 0; tj < 4; tj++)
        acc[ti*4+tj] = __builtin_amdgcn_mfma_f32_16x16x32_bf16(
                           av, bv[tj], acc[ti*4+tj], 0, 0, 0);
    }
  }

  // epilogue: out += acc; capture final values for next layer's BN stats.
  float s = 0.f, s2 = 0.f;
  #pragma unroll
  for (int tj = 0; tj < 4; tj++) {
    int t = tj*16 + l15;
    float* obase = out + (((size_t)b*C_ + o)*N_)*T_ + t;
    #pragma unroll
    for (int ti = 0; ti < 2; ti++) {
      int wbase = w0 + wi*32 + ti*16 + quad*4;
      #pragma unroll
      for (int r = 0; r < 4; r++) {
        int w = wbase + r;
        if (w < N_) {
          float* p = obase + (size_t)w*T_;
          float val = *p + acc[ti*4+tj][r];
          *p = val;
          s += val;
          s2 = fmaf(val, val, s2);
        }
      }
    }
  }
  if (stp) {
    #pragma unroll
    for (int d = 32; d > 0; d >>= 1) {
      s  += __shfl_down(s,  d, 64);
      s2 += __shfl_down(s2, d, 64);
    }
    if (lane == 0) {
      atomicAdd(&stp[2*o],     (double)s);
      atomicAdd(&stp[2*o + 1], (double)s2);
    }
  }
}

// ---------------------------------------------------------------------------
// Online-softmax attention, one node per wave, MLP fully in registers.
__global__ __launch_bounds__(256) void attn3_kernel(
    const float* __restrict__ hsrc, float* __restrict__ O,
    float* __restrict__ sden,
    const float* __restrict__ W1T, const float* __restrict__ b1,
    const float* __restrict__ W2, const float* __restrict__ b2,
    const float* __restrict__ w3, const float* __restrict__ b3,
    int init)
{
  int tid = threadIdx.x;
  int t = tid & 63;
  int g = __builtin_amdgcn_readfirstlane(tid >> 6);
  int bx = blockIdx.x;
  int b = bx / 125;
  int n = (bx - b*125)*4 + g;
  size_t off = (size_t)b*BSTR + (size_t)n*T_;

  float h1r[64];
  #pragma unroll
  for (int k = 0; k < 64; k++) h1r[k] = b1[k];
  for (int c = 0; c < C_; c++) {
    float xv = fmaxf(hsrc[off + (size_t)c*CSTR + t], 0.f);
    const float* wr = W1T + c*64;
    #pragma unroll
    for (int k = 0; k < 64; k++) h1r[k] = fmaf(wr[k], xv, h1r[k]);
  }
  #pragma unroll
  for (int k = 0; k < 64; k++) h1r[k] = fmaxf(h1r[k], 0.f);

  float e = b3[0];
  for (int j = 0; j < 64; j++) {
    const float* w2r = W2 + j*64;
    float a0 = 0.f, a1 = 0.f, a2 = 0.f, a3 = 0.f;
    #pragma unroll
    for (int i = 0; i < 64; i += 4) {
      a0 = fmaf(w2r[i+0], h1r[i+0], a0);
      a1 = fmaf(w2r[i+1], h1r[i+1], a1);
      a2 = fmaf(w2r[i+2], h1r[i+2], a2);
      a3 = fmaf(w2r[i+3], h1r[i+3], a3);
    }
    float a = b2[j] + ((a0+a1)+(a2+a3));
    e = fmaf(w3[j], fmaxf(a, 0.f), e);
  }
  float p = expf(e);      // e is O(1): no max-subtraction needed

  size_t si = (size_t)b*CSTR + (size_t)n*T_ + t;
  float so = init ? 0.f : sden[si];
  sden[si] = so + p;

  for (int c = 0; c < C_; c++) {
    size_t pi = off + (size_t)c*CSTR + t;
    float xv = fmaxf(hsrc[pi], 0.f);      // L1-hit re-read
    float ov = init ? 0.f : O[pi];
    O[pi] = fmaf(p, xv, ov);
  }
}

// ---------------------------------------------------------------------------
__global__ __launch_bounds__(256) void norm_kernel(float* __restrict__ O,
                                                   const float* __restrict__ sden) {
  unsigned idx = (blockIdx.x*256u + threadIdx.x) * 4u;
  unsigned b = idx / BSTR;
  unsigned r = idx - b*BSTR;
  unsigned nt = r % CSTR;
  float4 o = *(float4*)(O + idx);
  const float* sp = sden + (size_t)b*CSTR + nt;
  o.x /= sp[0]; o.y /= sp[1]; o.z /= sp[2]; o.w /= sp[3];
  *(float4*)(O + idx) = o;
}

// ---------------------------------------------------------------------------
extern "C" void kernel_launch(void* const* d_in, const int* in_sizes, int n_in,
                              void* d_out, int out_size, void* d_ws, size_t ws_size,
                              hipStream_t stream)
{
  const float* x    = (const float*)d_in[0];
  const float* sup  = (const float*)d_in[1];
  const float* bng  = (const float*)d_in[2];
  const float* bnb  = (const float*)d_in[3];
  const float* rw   = (const float*)d_in[4];
  const float* rb   = (const float*)d_in[5];
  const float* aw   = (const float*)d_in[6];
  const float* ab   = (const float*)d_in[7];
  const float* gw   = (const float*)d_in[8];
  const float* gb   = (const float*)d_in[9];
  const float* gcw  = (const float*)d_in[10];
  const float* gcb  = (const float*)d_in[11];
  const float* w1   = (const float*)d_in[12];
  const float* ab1  = (const float*)d_in[13];
  const float* w2   = (const float*)d_in[14];
  const float* ab2  = (const float*)d_in[15];
  const float* w3   = (const float*)d_in[16];
  const float* ab3  = (const float*)d_in[17];
  float* out = (float*)d_out;

  // ws layout (floats; total 49,957,904 fl = 190.6 MiB < prior 191.6 MiB):
  float* ws   = (float*)d_ws;
  float* bufA = ws;                                   // TENS
  u16*   Y1h  = (u16*)(ws + TENS);                    // TENS u16
  u16*   Y2h  = Y1h + TENS;                           // TENS u16
  u16*   Yt   = (u16*)(ws + (size_t)2*TENS);          // 16*2048*1000 u16
  float* slack= ws + (size_t)2*TENS + 16384000;       // 16 fl (Yt spill guard)
  float* sden = slack + 16;                           // 512000
  double* st  = (double*)(sden + (size_t)B_*N_*T_);   // 512 dbl
  short* ATh  = (short*)((float*)st + 1024);          // 512*1024 shorts
  float* W1T  = (float*)(ATh + (size_t)512*1024);     // 2048
  u16* WAGh = (u16*)(W1T + 2048);                     // [L][3][64][32]
  u16* WAGl = WAGh + 24576;
  u16* WRh  = WAGl + 24576;                           // [L][32][32]
  u16* WRl  = WRh + 4096;

  zero_kernel<<<1, 256, 0, stream>>>(st, slack);
  aconv_kernel<<<2048, 256, 0, stream>>>(sup, ATh);
  w1t_kernel<<<8, 256, 0, stream>>>(w1, W1T);
  wprep_kernel<<<112, 256, 0, stream>>>(aw, gw, rw, WAGh, WAGl, WRh, WRl);
  stats_kernel<<<dim3(C_, B_), 256, 0, stream>>>(x, st);
  // slot 0 of the stack = x
  attn3_kernel<<<B_*125, 256, 0, stream>>>(x, out, sden, W1T, ab1, w2, ab2, w3, ab3, 1);

  const float* hcur = x;
  for (int l = 0; l < L_; l++) {
    fuse4_kernel<<<B_*250, 512, 0, stream>>>(
        hcur, st + l*64, bng + l*C_, bnb + l*C_,
        WAGh + l*6144, WAGl + l*6144, WRh + l*1024, WRl + l*1024,
        rb + l*C_, ab + l*C_, gb + l*C_,
        gcw + l*C_*96, gcb + l*C_,
        bufA, Y1h, Y2h);
    trans_kernel<<<dim3(128, B_), 256, 0, stream>>>(Y1h, Y2h, Yt);
    diff6_kernel<<<dim3(128, B_), 256, 0, stream>>>(
        Yt, ATh, bufA, (l < L_-1) ? (st + (l+1)*64) : nullptr);
    attn3_kernel<<<B_*125, 256, 0, stream>>>(bufA, out, sden, W1T, ab1, w2, ab2, w3, ab3, 0);
    hcur = bufA;
  }
  norm_kernel<<<16000, 256, 0, stream>>>(out, sden);
}

// Round 9
// 1582.475 us; speedup vs baseline: 1.0927x; 1.0348x over previous
//
#include <hip/hip_runtime.h>
#include <hip/hip_bf16.h>
#include <math.h>

#define B_ 16
#define C_ 32
#define N_ 500
#define T_ 64
#define L_ 4
#define BSTR (C_*N_*T_)              // 1024000
#define CSTR (N_*T_)                 // 32000
#define TENS ((size_t)B_*C_*N_*T_)   // 16384000
#define CNT_ 512000.0

typedef short s8v __attribute__((ext_vector_type(8)));
typedef float f4v __attribute__((ext_vector_type(4)));
typedef unsigned short u16;

// ---------------------------------------------------------------------------
__global__ __launch_bounds__(256) void zero_kernel(double* __restrict__ p,
                                                   float* __restrict__ slack) {
  p[threadIdx.x] = 0.0;   // 256 doubles = L_*64 stats slots
  if (threadIdx.x < 16) slack[threadIdx.x] = 0.f;  // Yt tail guard (NaN-safe)
}

// ---------------------------------------------------------------------------
// Per-channel sum/sum-sq for BN, layer 0 only (reads x). fp64 exact.
__global__ __launch_bounds__(256) void stats_kernel(const float* __restrict__ h,
                                                    double* __restrict__ st) {
  int c = blockIdx.x, b = blockIdx.y, tid = threadIdx.x;
  const float4* p = (const float4*)(h + (size_t)b*BSTR + (size_t)c*CSTR);
  double s = 0.0, s2 = 0.0;
  for (int i = tid; i < CSTR/4; i += 256) {
    float4 v = p[i];
    s  += (double)v.x + (double)v.y + (double)v.z + (double)v.w;
    s2 += (double)v.x*v.x + (double)v.y*v.y + (double)v.z*v.z + (double)v.w*v.w;
  }
  __shared__ double sd[256], sd2[256];
  sd[tid] = s; sd2[tid] = s2; __syncthreads();
  for (int off = 128; off > 0; off >>= 1) {
    if (tid < off) { sd[tid] += sd[tid+off]; sd2[tid] += sd2[tid+off]; }
    __syncthreads();
  }
  if (tid == 0) { atomicAdd(&st[2*c], sd[0]); atomicAdd(&st[2*c+1], sd2[0]); }
}

// ---------------------------------------------------------------------------
// Build ATcat[w][k] bf16 single plane, w<512 (pad), k-map: [0,500) sup1 v=k,
// [500,1000) sup2 v=k-500, [1000,1024) ZERO (guards B's row-spill reads).
__global__ __launch_bounds__(256) void aconv_kernel(const float* __restrict__ sup,
                                                    short* __restrict__ ATh) {
  int idx = blockIdx.x*256 + threadIdx.x;   // 512*1024
  int k = idx & 1023, w = idx >> 10;
  float val = 0.f;
  if (k < 1000 && w < N_) {
    int s = k >= 500;
    int v = k - s*500;
    val = sup[((size_t)s*N_ + v)*N_ + w];
  }
  __hip_bfloat16 bh = __float2bfloat16(val);
  ATh[idx] = *(short*)&bh;
}

// ---------------------------------------------------------------------------
// Weight prep: fuse4 B-fragments (split bf16) + attn W1/W2 single-plane bf16.
__global__ __launch_bounds__(256) void wprep_kernel(
    const float* __restrict__ aw, const float* __restrict__ gw,
    const float* __restrict__ rw,
    const float* __restrict__ w1, const float* __restrict__ w2,
    u16* __restrict__ wagh, u16* __restrict__ wagl,
    u16* __restrict__ wrh,  u16* __restrict__ wrl,
    u16* __restrict__ W1bf, u16* __restrict__ W2bf)
{
  int idx = blockIdx.x*256 + threadIdx.x;   // 0..34815
  if (idx >= 34816) return;
  if (idx >= 28672) {                       // attn weights, single plane
    int j = idx - 28672;
    if (j < 2048) {
      __hip_bfloat16 bv = __float2bfloat16(w1[j]);
      W1bf[j] = *(u16*)&bv;
    } else {
      __hip_bfloat16 bv = __float2bfloat16(w2[j - 2048]);
      W2bf[j - 2048] = *(u16*)&bv;
    }
    return;
  }
  float v; u16 *dh, *dl; int di;
  if (idx < 24576) {
    int l = idx / 6144, r = idx % 6144;
    int tap = r / 2048, col = (r >> 5) & 63, c = r & 31;
    v = (col < 32) ? aw[l*3072 + (col*32 + c)*3 + tap]
                   : gw[l*3072 + ((col-32)*32 + c)*3 + tap];
    dh = wagh; dl = wagl; di = idx;
  } else {
    int j = idx - 24576;
    int l = j >> 10, o = (j >> 5) & 31, c = j & 31;
    v = rw[l*1024 + o*32 + c];
    dh = wrh; dl = wrl; di = j;
  }
  __hip_bfloat16 bh = __float2bfloat16(v);
  float fh = __bfloat162float(bh);
  __hip_bfloat16 bl = __float2bfloat16(v - fh);
  dh[di] = *(u16*)&bh;
  dl[di] = *(u16*)&bl;
}

// ---------------------------------------------------------------------------
// MFMA fuse: BN -> ReLU -> split-bf16 {res 1x1, causal convs K=3} on matrix
// cores -> tanh*sigmoid in C-fragments -> z to LDS -> VALU 32x96 mix.
// Writes Y0 (float) + Y1h/Y2h (bf16 [o][n][t]).
__global__ __launch_bounds__(512) void fuse4_kernel(
    const float* __restrict__ h, const double* __restrict__ st,
    const float* __restrict__ gamma, const float* __restrict__ beta,
    const u16* __restrict__ wagh, const u16* __restrict__ wagl,
    const u16* __restrict__ wrh,  const u16* __restrict__ wrl,
    const float* __restrict__ rb, const float* __restrict__ ab,
    const float* __restrict__ gb,
    const float* __restrict__ gcw, const float* __restrict__ gcb,
    float* __restrict__ Y0, u16* __restrict__ Y1h, u16* __restrict__ Y2h)
{
  __shared__ __align__(16) char smem[41600];
  __shared__ float ssc[C_], ssb[C_];
  u16* Sxh = (u16*)smem;          // x planes [132 rows][40] (2 pad rows/node)
  u16* Sxl = Sxh + 5280;
  u16* Shh = Sxl + 5280;          // h planes [128][40]
  u16* Shl = Shh + 5120;
  float* Sz = (float*)smem;       // overlay after GEMM: z [2][32*65]

  int tid = threadIdx.x;
  int bx  = blockIdx.x;
  int b = bx / 250, np = bx - b*250;
  size_t off0 = (size_t)b*BSTR + (size_t)(np*2)*T_;

  // ---- stage: 8 f32/thread (coalesced: consecutive tid -> consecutive m)
  int m  = tid & 127;             // m = nn*64 + t  (T_=64)
  int c0 = (tid >> 7) << 3;       // 8-channel group
  float hv[8];
  #pragma unroll
  for (int j = 0; j < 8; j++)
    hv[j] = h[off0 + (size_t)(c0 + j)*CSTR + m];

  if (tid < C_) {
    double mm = st[2*tid] * (1.0/CNT_);
    double vv = st[2*tid+1] * (1.0/CNT_) - mm*mm;
    float sc = gamma[tid] * (float)(1.0 / sqrt(vv + 1e-5));
    ssc[tid] = sc;
    ssb[tid] = beta[tid] - (float)mm * sc;
  }
  __syncthreads();

  union P { u16 s[8]; int4 v; };
  P hh8, hl8, xh8, xl8;
  #pragma unroll
  for (int j = 0; j < 8; j++) {
    float hval = hv[j];
    __hip_bfloat16 t1 = __float2bfloat16(hval);
    hh8.s[j] = *(u16*)&t1;
    __hip_bfloat16 t2 = __float2bfloat16(hval - __bfloat162float(t1));
    hl8.s[j] = *(u16*)&t2;
    float xval = fmaxf(fmaf(hval, ssc[c0+j], ssb[c0+j]), 0.f);
    __hip_bfloat16 t3 = __float2bfloat16(xval);
    xh8.s[j] = *(u16*)&t3;
    __hip_bfloat16 t4 = __float2bfloat16(xval - __bfloat162float(t3));
    xl8.s[j] = *(u16*)&t4;
  }
  *(int4*)&Shh[m*40 + c0] = hh8.v;
  *(int4*)&Shl[m*40 + c0] = hl8.v;
  int xrow = m + 2 + (m >> 6)*2;  // node*66 + tloc + 2
  *(int4*)&Sxh[xrow*40 + c0] = xh8.v;
  *(int4*)&Sxl[xrow*40 + c0] = xl8.v;
  if (tid < 32) {                 // zero pad rows {0,1,66,67} x 2 planes
    int pl = tid >> 4, rsel = (tid >> 2) & 3, ch = tid & 3;
    int row = (rsel & 1) + (rsel >> 1)*66;
    int4 z4 = {0,0,0,0};
    *(int4*)((pl ? Sxl : Sxh) + row*40 + ch*8) = z4;
  }
  __syncthreads();

  // ---- GEMM phase: wave -> 16-row m-tile (node, t0), all 32 out channels
  int lane = tid & 63;
  int wave = __builtin_amdgcn_readfirstlane(tid >> 6);
  int node = wave >> 2, t0 = (wave & 3) << 4;
  int l15 = lane & 15, q = lane >> 4;

  f4v affc[2], gatec[2], resc[2];
  #pragma unroll
  for (int i = 0; i < 2; i++) {
    affc[i] = (f4v){0.f,0.f,0.f,0.f};
    gatec[i] = (f4v){0.f,0.f,0.f,0.f};
    resc[i] = (f4v){0.f,0.f,0.f,0.f};
  }

  {   // res: A = h planes, K=32
    int ha = (node*64 + t0 + l15)*40 + q*8;
    s8v hhf = *(const s8v*)&Shh[ha];
    s8v hlf = *(const s8v*)&Shl[ha];
    #pragma unroll
    for (int ct = 0; ct < 2; ct++) {
      int wb = (ct*16 + l15)*32 + q*8;
      s8v wh = *(const s8v*)&wrh[wb];
      s8v wl = *(const s8v*)&wrl[wb];
      f4v d = resc[ct];
      d = __builtin_amdgcn_mfma_f32_16x16x32_bf16(hhf, wh, d, 0, 0, 0);
      d = __builtin_amdgcn_mfma_f32_16x16x32_bf16(hlf, wh, d, 0, 0, 0);
      d = __builtin_amdgcn_mfma_f32_16x16x32_bf16(hhf, wl, d, 0, 0, 0);
      resc[ct] = d;
    }
  }
  #pragma unroll
  for (int tap = 0; tap < 3; tap++) {   // causal conv = 3 shifted-row GEMMs
    int xa = (node*66 + t0 + l15 + tap)*40 + q*8;
    s8v xhf = *(const s8v*)&Sxh[xa];
    s8v xlf = *(const s8v*)&Sxl[xa];
    #pragma unroll
    for (int ct = 0; ct < 4; ct++) {    // 0,1 aff cols; 2,3 gate cols
      int wb = (tap*64 + ct*16 + l15)*32 + q*8;
      s8v wh = *(const s8v*)&wagh[wb];
      s8v wl = *(const s8v*)&wagl[wb];
      f4v d = (ct < 2) ? affc[ct] : gatec[ct-2];
      d = __builtin_amdgcn_mfma_f32_16x16x32_bf16(xhf, wh, d, 0, 0, 0);
      d = __builtin_amdgcn_mfma_f32_16x16x32_bf16(xlf, wh, d, 0, 0, 0);
      d = __builtin_amdgcn_mfma_f32_16x16x32_bf16(xhf, wl, d, 0, 0, 0);
      if (ct < 2) affc[ct] = d; else gatec[ct-2] = d;
    }
  }
  __syncthreads();   // all LDS A-reads done before z overlays the planes

  // ---- combine in C-fragment layout: col=o=l15(+16ct), row m=t0+q*4+r
  #pragma unroll
  for (int ct = 0; ct < 2; ct++) {
    int o = ct*16 + l15;
    float abias = ab[o] + rb[o];
    float gbias = gb[o];
    #pragma unroll
    for (int r = 0; r < 4; r++) {
      float a = affc[ct][r] + resc[ct][r] + abias;
      float g = gatec[ct][r] + gbias;
      float z = tanhf(a) * (1.f/(1.f + expf(-g)));
      Sz[node*2080 + o*65 + (t0 + q*4 + r)] = z;
    }
  }
  __syncthreads();

  // ---- mix: three 32x32 pointwise GEMMs on VALU (proven epilogue)
  int t = tid & 63;
  int og = wave;
  float y0a[2][4] = {}, y1a[2][4] = {}, y2a[2][4] = {};
  for (int c = 0; c < C_; c++) {
    float g0[4], g1[4], g2[4];
    #pragma unroll
    for (int jq = 0; jq < 4; jq++) {
      const float* gr = gcw + (og*4 + jq)*96;
      g0[jq] = gr[c]; g1[jq] = gr[32 + c]; g2[jq] = gr[64 + c];
    }
    #pragma unroll
    for (int nn = 0; nn < 2; nn++) {
      float zc = Sz[nn*2080 + c*65 + t];
      #pragma unroll
      for (int jq = 0; jq < 4; jq++) {
        y0a[nn][jq] = fmaf(g0[jq], zc, y0a[nn][jq]);
        y1a[nn][jq] = fmaf(g1[jq], zc, y1a[nn][jq]);
        y2a[nn][jq] = fmaf(g2[jq], zc, y2a[nn][jq]);
      }
    }
  }
  #pragma unroll
  for (int nn = 0; nn < 2; nn++)
    #pragma unroll
    for (int jq = 0; jq < 4; jq++) {
      int oo = og*4 + jq;
      size_t pp = off0 + (size_t)nn*T_ + (size_t)oo*CSTR + t;
      Y0[pp] = y0a[nn][jq] + gcb[oo];
      __hip_bfloat16 b1 = __float2bfloat16(y1a[nn][jq]);
      __hip_bfloat16 b2 = __float2bfloat16(y2a[nn][jq]);
      Y1h[pp] = *(u16*)&b1;
      Y2h[pp] = *(u16*)&b2;
    }
}

// ---------------------------------------------------------------------------
// Transpose Y1h/Y2h [o][n][t] -> Yt [b][(o*64+t)][1000 v-contig] (v<500 sup1,
// 500..999 sup2), zero-padding internally. LDS 64x68 tile; paired b32 reads.
__global__ __launch_bounds__(256) void trans_kernel(
    const u16* __restrict__ Y1h, const u16* __restrict__ Y2h,
    u16* __restrict__ Yt)
{
  __shared__ u16 S[64*68];
  int bx = blockIdx.x;
  int o = bx & 31, vg = bx >> 5;       // 32 o x 4 vgroups
  int b = blockIdx.y;
  int tid = threadIdx.x;
  u16* dst = Yt + (size_t)(b*C_ + o)*64000;
  for (int ic = 0; ic < 4; ic++) {
    int vc = vg*4 + ic;                // 64-v chunk, 0..15
    __syncthreads();
    #pragma unroll
    for (int i = 0; i < 2; i++) {
      int vrow = (tid >> 3) + i*32;
      int vv = vc*64 + vrow;           // concat-v 0..1023
      int t8 = (tid & 7)*8;
      int4 val = {0,0,0,0};
      if (vv < 1000) {
        int sup = vv >= 500;
        int n = vv - sup*500;
        const u16* src = (sup ? Y2h : Y1h) + (size_t)b*BSTR + (size_t)o*CSTR
                         + (size_t)n*T_;
        val = *(const int4*)(src + t8);
      }
      *(int4*)&S[vrow*68 + t8] = val;
    }
    __syncthreads();
    int t2 = tid >> 3, vs = tid & 7;   // t = 2*t2, 2*t2+1; v-oct vs
    if (vc < 15 || vs < 5) {           // rows >= 1000 don't exist in dst
      unsigned r[8];
      #pragma unroll
      for (int j = 0; j < 8; j++)
        r[j] = *(const unsigned*)&S[(vs*8 + j)*68 + 2*t2];
      u16 lo[8], hi[8];
      #pragma unroll
      for (int j = 0; j < 8; j++) { lo[j] = (u16)r[j]; hi[j] = (u16)(r[j] >> 16); }
      *(int4*)(dst + (size_t)(2*t2)*1000   + vc*64 + vs*8) = *(const int4*)lo;
      *(int4*)(dst + (size_t)(2*t2+1)*1000 + vc*64 + vs*8) = *(const int4*)hi;
    }
  }
}

// ---------------------------------------------------------------------------
// Diffusion GEMM v6 (proven r8): 2-barrier LDS schedule + trans'd Yt +
// single-plane A. Per k-step/thread: 3 coalesced int4 loads -> 3 ds_writes
// -> 8 MFMA. 2-D grid natural order (L3 absorbs 16-block-distance B reuse).
__global__ __launch_bounds__(256) void diff6_kernel(
    const u16* __restrict__ Yt,
    const short* __restrict__ ATh,
    float* __restrict__ out, double* __restrict__ stp)
{
  __shared__ short Asd[64*40];       // AT tile [w_local][k(32)+pad8]
  __shared__ short Bsd[128*40];      // Y  tile [m=(oo,t)][k(32)+pad8]

  int tid = threadIdx.x;
  int bx = blockIdx.x;
  int mtile = bx & 15, wtile = bx >> 4;   // 16 mtiles x 8 wtiles
  int b = blockIdx.y;
  int w0 = wtile << 6;

  int lane = tid & 63;
  int wave = __builtin_amdgcn_readfirstlane(tid >> 6);
  int wi = wave & 1, wj = wave >> 1;
  int l15 = lane & 15, quad = lane >> 4;
  int o = mtile*2 + wj;

  int offA[2], offB[4];
  #pragma unroll
  for (int ti = 0; ti < 2; ti++) offA[ti] = (wi*32 + ti*16 + l15)*40 + quad*8;
  #pragma unroll
  for (int tj = 0; tj < 4; tj++) offB[tj] = (wj*64 + tj*16 + l15)*40 + quad*8;

  // staging maps (coalesced: consecutive tid -> consecutive 16B within row)
  int akq = tid & 3, awl = tid >> 2;                 // A: 256 int4 = 64r x 4
  const short* aSrc = ATh + (size_t)(w0 + awl)*1024 + akq*8;
  short* aDst = &Asd[awl*40 + akq*8];
  const u16* bSrc[2]; short* bDst[2];
  #pragma unroll
  for (int i = 0; i < 2; i++) {                      // B: 512 int4 = 128r x 4
    int idx = tid + i*256;
    int kq = idx & 3, m = idx >> 2;
    int oo = m >> 6, tl = m & 63;
    bSrc[i] = Yt + ((size_t)(b*C_ + mtile*2 + oo)*64 + tl)*1000 + kq*8;
    bDst[i] = &Bsd[m*40 + kq*8];
  }

  f4v acc[8];
  #pragma unroll
  for (int i = 0; i < 8; i++) acc[i] = (f4v){0.f, 0.f, 0.f, 0.f};

  for (int k0 = 0; k0 < 1024; k0 += 32) {
    __syncthreads();
    *(int4*)aDst    = *(const int4*)(aSrc    + k0);
    *(int4*)bDst[0] = *(const int4*)(bSrc[0] + k0);
    *(int4*)bDst[1] = *(const int4*)(bSrc[1] + k0);
    __syncthreads();
    s8v bv[4];
    #pragma unroll
    for (int tj = 0; tj < 4; tj++) bv[tj] = *(const s8v*)&Bsd[offB[tj]];
    #pragma unroll
    for (int ti = 0; ti < 2; ti++) {
      s8v av = *(const s8v*)&Asd[offA[ti]];
      #pragma unroll
      for (int tj = 0; tj < 4; tj++)
        acc[ti*4+tj] = __builtin_amdgcn_mfma_f32_16x16x32_bf16(
                           av, bv[tj], acc[ti*4+tj], 0, 0, 0);
    }
  }

  // epilogue: out += acc; capture final values for next layer's BN stats.
  float s = 0.f, s2 = 0.f;
  #pragma unroll
  for (int tj = 0; tj < 4; tj++) {
    int t = tj*16 + l15;
    float* obase = out + (((size_t)b*C_ + o)*N_)*T_ + t;
    #pragma unroll
    for (int ti = 0; ti < 2; ti++) {
      int wbase = w0 + wi*32 + ti*16 + quad*4;
      #pragma unroll
      for (int r = 0; r < 4; r++) {
        int w = wbase + r;
        if (w < N_) {
          float* p = obase + (size_t)w*T_;
          float val = *p + acc[ti*4+tj][r];
          *p = val;
          s += val;
          s2 = fmaf(val, val, s2);
        }
      }
    }
  }
  if (stp) {
    #pragma unroll
    for (int d = 32; d > 0; d >>= 1) {
      s  += __shfl_down(s,  d, 64);
      s2 += __shfl_down(s2, d, 64);
    }
    if (lane == 0) {
      atomicAdd(&stp[2*o],     (double)s);
      atomicAdd(&stp[2*o + 1], (double)s2);
    }
  }
}

// ---------------------------------------------------------------------------
// attn v4: MLP on matrix cores, one node per wave, no cross-wave barriers.
// GEMM1 h1[64t][64j]=X[64t][32c]*W1^T (16 MFMA), GEMM2 (32 MFMA, K=64).
// x staged to per-wave LDS [t][40]; h1 overlaid same region [t][72] (reads
// precede writes in wave program order; DS pipe is in-order per wave).
// e-reduce: shfl_xor over 16-lane col groups; predicated static scatter.
__global__ __launch_bounds__(256) void attn4_kernel(
    const float* __restrict__ hsrc, float* __restrict__ O,
    float* __restrict__ sden,
    const u16* __restrict__ W1bf, const float* __restrict__ b1,
    const u16* __restrict__ W2bf, const float* __restrict__ b2,
    const float* __restrict__ w3, const float* __restrict__ b3,
    int init)
{
  __shared__ u16 Sh[4*4608];     // per-wave 4608 u16: x [64][40] / h1 [64][72]
  __shared__ float Se[4*64];

  int tid = threadIdx.x;
  int lane = tid & 63;
  int wave = __builtin_amdgcn_readfirstlane(tid >> 6);
  int bx = blockIdx.x;
  int b = bx / 125;
  int n = (bx - b*125)*4 + wave;
  size_t off = (size_t)b*BSTR + (size_t)n*T_;
  int l15 = lane & 15, q = lane >> 4;

  u16* R = Sh + wave*4608;
  float* Ew = Se + wave*64;

  // 1. load own-t column, relu, stage rows [t][c] (stride 40)
  float xv[32];
  #pragma unroll 8
  for (int c = 0; c < 32; c++)
    xv[c] = fmaxf(hsrc[off + (size_t)c*CSTR + lane], 0.f);
  #pragma unroll
  for (int c8 = 0; c8 < 4; c8++) {
    union { u16 s[8]; int4 v; } pk;
    #pragma unroll
    for (int j = 0; j < 8; j++) {
      __hip_bfloat16 bv = __float2bfloat16(xv[c8*8 + j]);
      pk.s[j] = *(u16*)&bv;
    }
    *(int4*)&R[lane*40 + c8*8] = pk.v;
  }

  // 2-3. GEMM1
  f4v c1[4][4];
  {
    s8v a1[4];
    #pragma unroll
    for (int mt = 0; mt < 4; mt++)
      a1[mt] = *(const s8v*)&R[(mt*16 + l15)*40 + q*8];
    #pragma unroll
    for (int jt = 0; jt < 4; jt++) {
      s8v w1f = *(const s8v*)&W1bf[(jt*16 + l15)*32 + q*8];
      #pragma unroll
      for (int mt = 0; mt < 4; mt++) {
        f4v z = (f4v){0.f, 0.f, 0.f, 0.f};
        c1[mt][jt] = __builtin_amdgcn_mfma_f32_16x16x32_bf16(a1[mt], w1f, z, 0, 0, 0);
      }
    }
  }
  // 4. h1 = relu(c1 + b1[j]) -> bf16 -> LDS [t][j] (stride 72)
  #pragma unroll
  for (int jt = 0; jt < 4; jt++) {
    float bb = b1[jt*16 + l15];
    #pragma unroll
    for (int mt = 0; mt < 4; mt++)
      #pragma unroll
      for (int r = 0; r < 4; r++) {
        float v = fmaxf(c1[mt][jt][r] + bb, 0.f);
        __hip_bfloat16 bv = __float2bfloat16(v);
        R[(mt*16 + q*4 + r)*72 + jt*16 + l15] = *(u16*)&bv;
      }
  }
  // 5. GEMM2 (K=64: 2 k-steps)
  f4v c2[4][4];
  #pragma unroll
  for (int mt = 0; mt < 4; mt++)
    #pragma unroll
    for (int jt = 0; jt < 4; jt++) c2[mt][jt] = (f4v){0.f, 0.f, 0.f, 0.f};
  #pragma unroll
  for (int ks = 0; ks < 2; ks++) {
    s8v a2[4];
    #pragma unroll
    for (int mt = 0; mt < 4; mt++)
      a2[mt] = *(const s8v*)&R[(mt*16 + l15)*72 + ks*32 + q*8];
    #pragma unroll
    for (int jt = 0; jt < 4; jt++) {
      s8v w2f = *(const s8v*)&W2bf[(jt*16 + l15)*64 + ks*32 + q*8];
      #pragma unroll
      for (int mt = 0; mt < 4; mt++)
        c2[mt][jt] = __builtin_amdgcn_mfma_f32_16x16x32_bf16(a2[mt], w2f, c2[mt][jt], 0, 0, 0);
    }
  }
  // 6. partial e (col j = jt*16+l15; row t = mt*16 + q*4 + r)
  float pe[4][4] = {};
  #pragma unroll
  for (int jt = 0; jt < 4; jt++) {
    float bb = b2[jt*16 + l15];
    float ww = w3[jt*16 + l15];
    #pragma unroll
    for (int mt = 0; mt < 4; mt++)
      #pragma unroll
      for (int r = 0; r < 4; r++)
        pe[mt][r] = fmaf(ww, fmaxf(c2[mt][jt][r] + bb, 0.f), pe[mt][r]);
  }
  // 7. reduce over the 16 col-lanes (masks < 16 keep quad groups)
  #pragma unroll
  for (int msk = 1; msk < 16; msk <<= 1)
    #pragma unroll
    for (int mt = 0; mt < 4; mt++)
      #pragma unroll
      for (int r = 0; r < 4; r++)
        pe[mt][r] += __shfl_xor(pe[mt][r], msk, 64);
  // 8. scatter e rows (predicated, static indices — avoids scratch)
  #pragma unroll
  for (int i = 0; i < 16; i++)
    if (l15 == i)
      Ew[(i >> 2)*16 + q*4 + (i & 3)] = pe[i >> 2][i & 3];
  // 9. softmax accumulate (e is O(1): no max-subtraction)
  float p = expf(Ew[lane] + b3[0]);
  size_t si = (size_t)b*CSTR + (size_t)n*T_ + lane;
  float so = init ? 0.f : sden[si];
  sden[si] = so + p;
  #pragma unroll 8
  for (int c = 0; c < 32; c++) {
    size_t pi = off + (size_t)c*CSTR + lane;
    float ov = init ? 0.f : O[pi];
    O[pi] = fmaf(p, xv[c], ov);
  }
}

// ---------------------------------------------------------------------------
__global__ __launch_bounds__(256) void norm_kernel(float* __restrict__ O,
                                                   const float* __restrict__ sden) {
  unsigned idx = (blockIdx.x*256u + threadIdx.x) * 4u;
  unsigned b = idx / BSTR;
  unsigned r = idx - b*BSTR;
  unsigned nt = r % CSTR;
  float4 o = *(float4*)(O + idx);
  const float* sp = sden + (size_t)b*CSTR + nt;
  o.x /= sp[0]; o.y /= sp[1]; o.z /= sp[2]; o.w /= sp[3];
  *(float4*)(O + idx) = o;
}

// ---------------------------------------------------------------------------
extern "C" void kernel_launch(void* const* d_in, const int* in_sizes, int n_in,
                              void* d_out, int out_size, void* d_ws, size_t ws_size,
                              hipStream_t stream)
{
  const float* x    = (const float*)d_in[0];
  const float* sup  = (const float*)d_in[1];
  const float* bng  = (const float*)d_in[2];
  const float* bnb  = (const float*)d_in[3];
  const float* rw   = (const float*)d_in[4];
  const float* rb   = (const float*)d_in[5];
  const float* aw   = (const float*)d_in[6];
  const float* ab   = (const float*)d_in[7];
  const float* gw   = (const float*)d_in[8];
  const float* gb   = (const float*)d_in[9];
  const float* gcw  = (const float*)d_in[10];
  const float* gcb  = (const float*)d_in[11];
  const float* w1   = (const float*)d_in[12];
  const float* ab1  = (const float*)d_in[13];
  const float* w2   = (const float*)d_in[14];
  const float* ab2  = (const float*)d_in[15];
  const float* w3   = (const float*)d_in[16];
  const float* ab3  = (const float*)d_in[17];
  float* out = (float*)d_out;

  // ws layout (same proven footprint; W1T slot replaced by attn bf16 weights)
  float* ws   = (float*)d_ws;
  float* bufA = ws;                                   // TENS
  u16*   Y1h  = (u16*)(ws + TENS);                    // TENS u16
  u16*   Y2h  = Y1h + TENS;                           // TENS u16
  u16*   Yt   = (u16*)(ws + (size_t)2*TENS);          // 16*2048*1000 u16
  float* slack= ws + (size_t)2*TENS + 16384000;       // 16 fl (Yt spill guard)
  float* sden = slack + 16;                           // 512000
  double* st  = (double*)(sden + (size_t)B_*N_*T_);   // 512 dbl
  short* ATh  = (short*)((float*)st + 1024);          // 512*1024 shorts
  u16* WAGh = (u16*)(ATh + (size_t)512*1024);         // [L][3][64][32]
  u16* WAGl = WAGh + 24576;
  u16* WRh  = WAGl + 24576;                           // [L][32][32]
  u16* WRl  = WRh + 4096;
  u16* W1bf = WRl + 4096;                             // [64][32]
  u16* W2bf = W1bf + 2048;                            // [64][64]

  zero_kernel<<<1, 256, 0, stream>>>(st, slack);
  aconv_kernel<<<2048, 256, 0, stream>>>(sup, ATh);
  wprep_kernel<<<136, 256, 0, stream>>>(aw, gw, rw, w1, w2,
                                        WAGh, WAGl, WRh, WRl, W1bf, W2bf);
  stats_kernel<<<dim3(C_, B_), 256, 0, stream>>>(x, st);
  // slot 0 of the stack = x
  attn4_kernel<<<B_*125, 256, 0, stream>>>(x, out, sden, W1bf, ab1, W2bf, ab2, w3, ab3, 1);

  const float* hcur = x;
  for (int l = 0; l < L_; l++) {
    fuse4_kernel<<<B_*250, 512, 0, stream>>>(
        hcur, st + l*64, bng + l*C_, bnb + l*C_,
        WAGh + l*6144, WAGl + l*6144, WRh + l*1024, WRl + l*1024,
        rb + l*C_, ab + l*C_, gb + l*C_,
        gcw + l*C_*96, gcb + l*C_,
        bufA, Y1h, Y2h);
    trans_kernel<<<dim3(128, B_), 256, 0, stream>>>(Y1h, Y2h, Yt);
    diff6_kernel<<<dim3(128, B_), 256, 0, stream>>>(
        Yt, ATh, bufA, (l < L_-1) ? (st + (l+1)*64) : nullptr);
    attn4_kernel<<<B_*125, 256, 0, stream>>>(bufA, out, sden, W1bf, ab1, W2bf, ab2, w3, ab3, 0);
    hcur = bufA;
  }
  norm_kernel<<<16000, 256, 0, stream>>>(out, sden);
}